// Round 2
// baseline (282.040 us; speedup 1.0000x reference)
//
#include <hip/hip_runtime.h>

// N=262144 sentences, B=16384 bags (uniform 16/bag, contiguous), D=768, C=53
#define SPB 16        // sentences per bag
#define DIM 768
#define NC  53
#define D4  (DIM/4)   // 192 float4 per row
#define KPT 12        // float4 per thread per sentence (192 / 16 threads)

__global__ __launch_bounds__(256) void bag_attn_fused(
    const float* __restrict__ x,      // [N][D]
    const float* __restrict__ W,      // [C][D]
    const float* __restrict__ bias,   // [C]
    const int*   __restrict__ scope,  // [B+1]
    const int*   __restrict__ query,  // [N]
    float*       __restrict__ out)    // [B][C]
{
    const int b    = blockIdx.x;
    const int t    = threadIdx.x;
    const int g    = t >> 4;   // sentence 0..15
    const int j    = t & 15;   // lane within sentence group
    const int wave = t >> 6;   // 0..3
    const int l    = t & 63;   // lane within wave

    __shared__ float  att_lds[SPB];
    __shared__ float4 part4[SPB][D4];   // 48 KiB: weighted per-sentence vectors
    __shared__ float4 repre4[D4];       // 3 KiB: combined bag representation

    const int start = scope[b];         // bags contiguous, 16 each
    const int q     = query[start + g];

    const float4* x4 = reinterpret_cast<const float4*>(x) + (size_t)(start + g) * D4;
    const float4* w4 = reinterpret_cast<const float4*>(W) + (size_t)q * D4;

    // ---- att[s] = <x_s, W[q_s]>; x fragments stay in registers ----
    float4 xr[KPT];
    float att = 0.f;
    #pragma unroll
    for (int k = 0; k < KPT; ++k) {
        const float4 xv = x4[j + 16 * k];
        const float4 wv = w4[j + 16 * k];
        xr[k] = xv;
        att += xv.x * wv.x + xv.y * wv.y + xv.z * wv.z + xv.w * wv.w;
    }
    #pragma unroll
    for (int m = 8; m >= 1; m >>= 1)       // reduce within the 16-lane group
        att += __shfl_xor(att, m, 64);
    if (j == 0) att_lds[g] = att;
    __syncthreads();

    // ---- softmax over 16 scores (redundant per thread, VALU-cheap) ----
    float mx = att_lds[0];
    #pragma unroll
    for (int i = 1; i < SPB; ++i) mx = fmaxf(mx, att_lds[i]);
    float z = 0.f;
    #pragma unroll
    for (int i = 0; i < SPB; ++i) z += __expf(att_lds[i] - mx);
    const float wgt = __expf(att - mx) / z;

    // ---- weighted vectors straight to LDS (no shuffles) ----
    #pragma unroll
    for (int k = 0; k < KPT; ++k) {
        float4 v = xr[k];
        v.x *= wgt; v.y *= wgt; v.z *= wgt; v.w *= wgt;
        part4[g][j + 16 * k] = v;        // 12 x ds_write_b128
    }
    __syncthreads();

    // ---- combine 16 sentence partials -> repre (192 threads) ----
    if (t < D4) {
        float4 acc = part4[0][t];
        #pragma unroll
        for (int s = 1; s < SPB; ++s) {
            const float4 p = part4[s][t];
            acc.x += p.x; acc.y += p.y; acc.z += p.z; acc.w += p.w;
        }
        repre4[t] = acc;
    }
    __syncthreads();

    // ---- each wave holds the FULL repre in registers (3 b128 reads) ----
    const float4 rr0 = repre4[l];
    const float4 rr1 = repre4[l + 64];
    const float4 rr2 = repre4[l + 128];

    const float4* W4 = reinterpret_cast<const float4*>(W);
    for (int c = wave; c < NC; c += 4) {
        const float4* wc = W4 + (size_t)c * D4;
        const float4 w0 = wc[l], w1 = wc[l + 64], w2 = wc[l + 128];
        float s = rr0.x*w0.x + rr0.y*w0.y + rr0.z*w0.z + rr0.w*w0.w
                + rr1.x*w1.x + rr1.y*w1.y + rr1.z*w1.z + rr1.w*w1.w
                + rr2.x*w2.x + rr2.y*w2.y + rr2.z*w2.z + rr2.w*w2.w;
        #pragma unroll
        for (int m = 32; m >= 1; m >>= 1)
            s += __shfl_xor(s, m, 64);
        if (l == 0) out[(size_t)b * NC + c] = s + bias[c];
    }
}

extern "C" void kernel_launch(void* const* d_in, const int* in_sizes, int n_in,
                              void* d_out, int out_size, void* d_ws, size_t ws_size,
                              hipStream_t stream) {
    const float* x     = (const float*)d_in[0];   // [N][768]
    const float* W     = (const float*)d_in[1];   // [53][768]
    const float* bias  = (const float*)d_in[2];   // [53]
    const int*   scope = (const int*)d_in[3];     // [B+1]
    const int*   query = (const int*)d_in[4];     // [N]
    float* out = (float*)d_out;                   // [B][53]

    const int num_bags = in_sizes[3] - 1;         // 16384

    bag_attn_fused<<<num_bags, 256, 0, stream>>>(x, W, bias, scope, query, out);
}